// Round 4
// baseline (609.327 us; speedup 1.0000x reference)
//
#include <hip/hip_runtime.h>
#include <math.h>

// GlmDSAMoEGate, round 7: round 6 design with the launch-config bug fixed.
// Round 6 crashed: prep_w grid was (2048,8) but kernel indexes k16 in [0,256)
// -> OOB write 8x past the 4MB workspace -> device abort. Grid restored to
// (NK16=256, E/32=8) as in rounds 4-5 (both passed, absmax 2e-3).
// Design (unchanged from round 6):
//  - BM=32, grid=512, NTH=512: wave = 32 experts x 32 tokens (acc 32 VGPR).
//    a_st UNIONed with val (disjoint phases) -> 33.9KB LDS; launch_bounds(512,4)
//    -> 2 independent blocks/CU (4 waves/SIMD). Cross-block overlap hides
//    barrier/vmcnt stalls -- the TLP rounds 4-5 lacked (Occ 10.5%, Mfma 13.7%).
//  - K-mega-tile = 128 (8 k16 phases, 1 barrier each). Each thread stages 32B
//    of x -> full ds_write_b128, XOR-by-s swizzle (write pos = chunk^s, read
//    pos = lane^s) -> reads permuted-contiguous (conflict-free), writes 2-way.
//  - x loads (nontemporal) issued BEFORE the barrier; B register-double-
//    buffered by half-mega-tile (4 phases ~ 400cy ahead of consumption).
// Math identical to rounds 4-5: fp32 -> fp16 hi + lo*2^12 split, 3 MFMA
// passes, logit = accA + accB*2^-12.

constexpr int H = 4096;
constexpr int E = 256;
constexpr int BM = 32;          // tokens per block
constexpr int NTH = 512;        // 8 waves
constexpr int TOPK = 8;
constexpr int NGROUP = 8;
constexpr int GSIZE = 32;
constexpr int TOPK_GROUP = 4;
constexpr float SCALE = 2.5f;
constexpr int NK16 = H / 16;    // 256 k16 slabs
constexpr int NMT = H / 128;    // 32 K-mega-tiles
constexpr float LO_SCALE = 4096.0f;       // 2^12
constexpr float LO_INV = 1.0f / 4096.0f;  // 2^-12

typedef _Float16 f16x8 __attribute__((ext_vector_type(8)));
typedef float f32x4 __attribute__((ext_vector_type(4)));
typedef float f32x16 __attribute__((ext_vector_type(16)));

// ---------------- kernel 0: W[E][H] fp32 -> fragment-linear fp16 hi/lo ------
// Frag for MFMA 32x32x16 tile (k16, n32): lane l holds B[k][n] with
// n = n32*32 + (l&31), k = k16*16 + (l>>5)*8 + j, j=0..7  (16B per lane).
// Layout: wswz[(k16*8 + n32)*1024 + hl*512 + l*8]  (halves). Total 4MB.
__global__ __launch_bounds__(64)
void prep_w_kernel(const float* __restrict__ w, _Float16* __restrict__ wswz) {
  const int l = threadIdx.x;        // 0..63
  const int k16 = blockIdx.x;       // 0..255
  const int n32 = blockIdx.y;       // 0..7
  const int e = n32 * 32 + (l & 31);
  const int h0 = k16 * 16 + (l >> 5) * 8;
  const float4* wp = (const float4*)(w + (size_t)e * H + h0);
  const float4 a = wp[0], b = wp[1];
  const float v[8] = {a.x, a.y, a.z, a.w, b.x, b.y, b.z, b.w};
  f16x8 hi, lo;
#pragma unroll
  for (int j = 0; j < 8; ++j) {
    const _Float16 h = (_Float16)v[j];
    hi[j] = h;
    lo[j] = (_Float16)((v[j] - (float)h) * LO_SCALE);  // exact residual, scaled
  }
  _Float16* dst = wswz + (size_t)(k16 * 8 + n32) * 1024 + (size_t)l * 8;
  *(f16x8*)dst = hi;
  *(f16x8*)(dst + 512) = lo;
}

// ---------------- kernel 1: fused gate -------------------------------------
__global__ __launch_bounds__(NTH, 4)
void moe_gate_kernel(const float* __restrict__ x,      // [T][H] fp32
                     const _Float16* __restrict__ wswz,// frag-linear hi/lo
                     const float* __restrict__ bias,   // [E]
                     float* __restrict__ out_idx,      // [T][8] (as float)
                     float* __restrict__ out_w) {      // [T][8]
  // a: [buf][s(k16 in mega-tile, 0..7)][hl][512 halves] = 32 KB
  // val: scores_for_choice, 32*257*4 = 32896 B.  Disjoint in time -> union.
  __shared__ __align__(16) union SM {
    _Float16 a[2][8][2][512];
    float val[BM][E + 1];
  } sm;
  __shared__ float sbias[E];

  const int tid = threadIdx.x;
  const int lane = tid & 63;
  const int wave = tid >> 6;         // 0..7 -> expert slice [32*wave, +32)
  const long t0 = (long)blockIdx.x * BM;

  if (tid < E) sbias[tid] = bias[tid];

  // A staging coords: thread -> (token ta, k-octet ko), 8 floats = 32B of x.
  // Chunk c = kh*32 + ta (kh = ko&1: which 8-k half of the k16), phase s = ko>>1.
  // Stored at pos = c ^ s (XOR swizzle; read side uses lane ^ s).
  const int ta = tid >> 4;           // 0..31 token
  const int ko = tid & 15;           // 0..15 k-octet within 128-k mega-tile
  const int sA = ko >> 1;            // k16 phase 0..7
  const int posA = (((ko & 1) << 5) | ta) ^ sA;
  const float* xp = x + (size_t)(t0 + ta) * H + ko * 8;

  // B frag base for this wave/lane; per-k16 stride = 8192 halves
  const _Float16* const bb = wswz + (size_t)wave * 1024 + (size_t)lane * 8;

  f32x16 accA, accB;
#pragma unroll
  for (int r = 0; r < 16; ++r) { accA[r] = 0.0f; accB[r] = 0.0f; }

  f16x8 b0[4][2], b1[4][2];          // half-mega-tile B register double buffer

  auto writeA = [&](int buf, f32x4 q0, f32x4 q1) {
    const float v[8] = {q0[0], q0[1], q0[2], q0[3], q1[0], q1[1], q1[2], q1[3]};
    f16x8 hv, lv;
#pragma unroll
    for (int j = 0; j < 8; ++j) {
      const _Float16 h = (_Float16)v[j];
      hv[j] = h;
      lv[j] = (_Float16)((v[j] - (float)h) * LO_SCALE);
    }
    _Float16* p = &sm.a[buf][sA][0][posA * 8];
    *(f16x8*)p = hv;
    *(f16x8*)(p + 512) = lv;         // hl stride = 512 halves
  };

  auto phase = [&](int buf, int s, const f16x8& bh, const f16x8& bl) {
    const int pos = (lane ^ s) * 8;
    const f16x8 ah = *(const f16x8*)&sm.a[buf][s][0][pos];
    const f16x8 al = *(const f16x8*)&sm.a[buf][s][1][pos];
    accA = __builtin_amdgcn_mfma_f32_32x32x16_f16(ah, bh, accA, 0, 0, 0);
    accB = __builtin_amdgcn_mfma_f32_32x32x16_f16(ah, bl, accB, 0, 0, 0);
    accB = __builtin_amdgcn_mfma_f32_32x32x16_f16(al, bh, accB, 0, 0, 0);
  };

  // ---- prologue: A mega-tile 0 staged into buf 0, B phases 0-3 into b0 ----
  {
    const f32x4 q0 = __builtin_nontemporal_load((const f32x4*)xp);
    const f32x4 q1 = __builtin_nontemporal_load((const f32x4*)xp + 1);
    writeA(0, q0, q1);
#pragma unroll
    for (int s = 0; s < 4; ++s) {
      const _Float16* bp = bb + (size_t)s * 8192;
      b0[s][0] = *(const f16x8*)bp;
      b0[s][1] = *(const f16x8*)(bp + 512);
    }
  }

  // ---- main loop: 32 mega-tiles, 1 barrier each ----
#pragma unroll 1
  for (int mt = 0; mt < NMT; ++mt) {
    const int buf = mt & 1;
    const bool more = (mt + 1 < NMT);
    f32x4 q0 = {}, q1 = {};
    if (more) {                      // x for mt+1: issue BEFORE the barrier
      xp += 128;
      q0 = __builtin_nontemporal_load((const f32x4*)xp);
      q1 = __builtin_nontemporal_load((const f32x4*)xp + 1);
    }
    __syncthreads();                 // A[buf] visible; prev reads retired
    // prefetch B phases 4-7 of this mega-tile (consumed in half 1)
#pragma unroll
    for (int s = 0; s < 4; ++s) {
      const _Float16* bp = bb + (size_t)(8 * mt + 4 + s) * 8192;
      b1[s][0] = *(const f16x8*)bp;
      b1[s][1] = *(const f16x8*)(bp + 512);
    }
    phase(buf, 0, b0[0][0], b0[0][1]);
    phase(buf, 1, b0[1][0], b0[1][1]);
    phase(buf, 2, b0[2][0], b0[2][1]);
    phase(buf, 3, b0[3][0], b0[3][1]);
    if (more) {                      // prefetch B phases 0-3 of mt+1
#pragma unroll
      for (int s = 0; s < 4; ++s) {
        const _Float16* bp = bb + (size_t)(8 * (mt + 1) + s) * 8192;
        b0[s][0] = *(const f16x8*)bp;
        b0[s][1] = *(const f16x8*)(bp + 512);
      }
    }
    phase(buf, 4, b1[0][0], b1[0][1]);
    phase(buf, 5, b1[1][0], b1[1][1]);
    phase(buf, 6, b1[2][0], b1[2][1]);
    phase(buf, 7, b1[3][0], b1[3][1]);
    if (more) writeA(buf ^ 1, q0, q1);
  }

  // ---- scores_for_choice into LDS (val overlays a_st: barrier first) ----
  __syncthreads();
  // C layout (32x32 MFMA): col = lane&31, row = (r&3) + 8*(r>>2) + 4*(lane>>5)
  {
    const int col = lane & 31;
    const int rbase = (lane >> 5) * 4;
    const int e = wave * 32 + col;
    const float be = sbias[e];
#pragma unroll
    for (int r = 0; r < 16; ++r) {
      const int row = (r & 3) + 8 * (r >> 2) + rbase;
      const float logit = accA[r] + accB[r] * LO_INV;
      const float s = 1.0f / (1.0f + expf(-logit));    // sigmoid
      sm.val[row][e] = s + be;                         // s_choice
    }
  }
  __syncthreads();

  // ---- per-token grouped top-k (1 thread/token, lax.top_k semantics) ----
  if (tid < BM) {
    const int t = tid;
    float gs[NGROUP];
#pragma unroll
    for (int g = 0; g < NGROUP; ++g) {
      float m1 = -1e30f, m2 = -1e30f;
      for (int jj = 0; jj < GSIZE; ++jj) {
        const float v = sm.val[t][g * GSIZE + jj];
        if (v > m1) { m2 = m1; m1 = v; }
        else if (v > m2) { m2 = v; }
      }
      gs[g] = m1 + m2;
    }
    unsigned selmask = 0;
#pragma unroll
    for (int r = 0; r < TOPK_GROUP; ++r) {
      float best = -1e30f; int bg = 0;
#pragma unroll
      for (int g = 0; g < NGROUP; ++g) {
        if (((selmask >> g) & 1u) == 0 && gs[g] > best) { best = gs[g]; bg = g; }
      }
      selmask |= 1u << bg;
    }
    unsigned long long picked[4] = {0ull, 0ull, 0ull, 0ull};
    int idx[TOPK];
    float wts[TOPK];
    float wsum = 0.f;
    for (int r = 0; r < TOPK; ++r) {
      float best = -1e30f; int be2 = 0; bool found = false;
      for (int ee = 0; ee < E; ++ee) {
        if ((picked[ee >> 6] >> (ee & 63)) & 1ull) continue;
        const float v = ((selmask >> (ee >> 5)) & 1u) ? sm.val[t][ee] : 0.0f;
        if (!found || v > best) { best = v; be2 = ee; found = true; }
      }
      picked[be2 >> 6] |= 1ull << (be2 & 63);
      idx[r] = be2;
      const float s = sm.val[t][be2] - sbias[be2];
      wts[r] = s;
      wsum += s;
    }
    const float inv = SCALE / (wsum + 1e-20f);
#pragma unroll
    for (int r = 0; r < TOPK; ++r) {
      out_idx[(t0 + t) * TOPK + r] = (float)idx[r];
      out_w[(t0 + t) * TOPK + r] = wts[r] * inv;
    }
  }
}

extern "C" void kernel_launch(void* const* d_in, const int* in_sizes, int n_in,
                              void* d_out, int out_size, void* d_ws, size_t ws_size,
                              hipStream_t stream) {
  const float* x = (const float*)d_in[0];     // (4,4096,4096) fp32
  const float* w = (const float*)d_in[1];     // (256,4096) fp32
  const float* bias = (const float*)d_in[2];  // (256,) fp32

  const int T = in_sizes[0] / H;              // 16384
  _Float16* wswz = (_Float16*)d_ws;           // 4 MB frag-linear hi/lo W
  float* out_idx = (float*)d_out;
  float* out_w = (float*)d_out + (size_t)T * TOPK;

  prep_w_kernel<<<dim3(NK16, E / 32), dim3(64), 0, stream>>>(w, wswz);
  moe_gate_kernel<<<dim3(T / BM), dim3(NTH), 0, stream>>>(x, wswz, bias, out_idx, out_w);
}

// Round 5
// 429.032 us; speedup vs baseline: 1.4202x; 1.4202x over previous
//
#include <hip/hip_runtime.h>
#include <math.h>

// GlmDSAMoEGate, round 8: make the B software pipeline REAL + parallel epilogue.
// Round 7 (325us) post-mortem: VGPR_Count=64 proved the compiler SANK the B
// prefetch (intended b0+b1 = 64 VGPR + acc/addr ~ 130 > launch_bounds cap 128)
// -> every phase stalled on L2 latency; plus serial 1-thread/token epilogue
// (~20k cy/block).
// Round 8:
//  - B pipeline: 4 rotating slots (32 VGPR). Phase s consumes slot s&3, then
//    issues the load for global phase s+4 into that slot (prefetch distance =
//    4 phases ~ 400cy >= L2 latency). Total regs ~100 < 128 cap -> no sinking.
//    sched_barrier(0) per phase pins loads; setprio(1) wraps MFMA clusters.
//  - Epilogue: 16 threads/token (512 = 32 tok x 16). Sub-lane caches its 16
//    experts in regs; group top-2 via shfl_xor pair-merge; top-4 groups
//    redundantly per lane; 8 argmax rounds via 16-lane shfl_xor reduce with
//    exact lax.top_k tie semantics (lowest index wins ties).
//  - A staging / XOR swizzle / union LDS / launch shape: unchanged from round 7
//    (passed, absmax 2e-3, conflicts 7x down).
// Math: fp32 -> fp16 hi + lo*2^12 split, 3 MFMA passes, logit = accA+accB*2^-12.

constexpr int H = 4096;
constexpr int E = 256;
constexpr int BM = 32;          // tokens per block
constexpr int NTH = 512;        // 8 waves
constexpr int TOPK = 8;
constexpr int NGROUP = 8;
constexpr int GSIZE = 32;
constexpr int TOPK_GROUP = 4;
constexpr float SCALE = 2.5f;
constexpr int NK16 = H / 16;    // 256 k16 slabs (global phases)
constexpr int NMT = H / 128;    // 32 K-mega-tiles
constexpr float LO_SCALE = 4096.0f;       // 2^12
constexpr float LO_INV = 1.0f / 4096.0f;  // 2^-12

typedef _Float16 f16x8 __attribute__((ext_vector_type(8)));
typedef float f32x4 __attribute__((ext_vector_type(4)));
typedef float f32x16 __attribute__((ext_vector_type(16)));

// ---------------- kernel 0: W[E][H] fp32 -> fragment-linear fp16 hi/lo ------
// Frag for MFMA 32x32x16 tile (k16, n32): lane l holds B[k][n] with
// n = n32*32 + (l&31), k = k16*16 + (l>>5)*8 + j, j=0..7  (16B per lane).
// Layout: wswz[(k16*8 + n32)*1024 + hl*512 + l*8]  (halves). Total 4MB.
__global__ __launch_bounds__(64)
void prep_w_kernel(const float* __restrict__ w, _Float16* __restrict__ wswz) {
  const int l = threadIdx.x;        // 0..63
  const int k16 = blockIdx.x;       // 0..255
  const int n32 = blockIdx.y;       // 0..7
  const int e = n32 * 32 + (l & 31);
  const int h0 = k16 * 16 + (l >> 5) * 8;
  const float4* wp = (const float4*)(w + (size_t)e * H + h0);
  const float4 a = wp[0], b = wp[1];
  const float v[8] = {a.x, a.y, a.z, a.w, b.x, b.y, b.z, b.w};
  f16x8 hi, lo;
#pragma unroll
  for (int j = 0; j < 8; ++j) {
    const _Float16 h = (_Float16)v[j];
    hi[j] = h;
    lo[j] = (_Float16)((v[j] - (float)h) * LO_SCALE);  // exact residual, scaled
  }
  _Float16* dst = wswz + (size_t)(k16 * 8 + n32) * 1024 + (size_t)l * 8;
  *(f16x8*)dst = hi;
  *(f16x8*)(dst + 512) = lo;
}

// ---------------- kernel 1: fused gate -------------------------------------
__global__ __launch_bounds__(NTH, 4)
void moe_gate_kernel(const float* __restrict__ x,      // [T][H] fp32
                     const _Float16* __restrict__ wswz,// frag-linear hi/lo
                     const float* __restrict__ bias,   // [E]
                     float* __restrict__ out_idx,      // [T][8] (as float)
                     float* __restrict__ out_w) {      // [T][8]
  // a: [buf][s(k16 in mega-tile, 0..7)][hl][512 halves] = 32 KB
  // val: scores_for_choice, 32*257*4 = 32896 B.  Disjoint in time -> union.
  __shared__ __align__(16) union SM {
    _Float16 a[2][8][2][512];
    float val[BM][E + 1];
  } sm;
  __shared__ float sbias[E];

  const int tid = threadIdx.x;
  const int lane = tid & 63;
  const int wave = tid >> 6;         // 0..7 -> expert slice [32*wave, +32)
  const long t0 = (long)blockIdx.x * BM;

  if (tid < E) sbias[tid] = bias[tid];

  // A staging coords: thread -> (token ta, k-octet ko), 8 floats = 32B of x.
  // Chunk c = kh*32 + ta (kh = ko&1), phase s = ko>>1. Write pos = c ^ s,
  // read pos = lane ^ s (XOR swizzle; reads permuted-contiguous).
  const int ta = tid >> 4;           // 0..31 token
  const int ko = tid & 15;           // 0..15 k-octet within 128-k mega-tile
  const int sA = ko >> 1;            // k16 phase 0..7
  const int posA = (((ko & 1) << 5) | ta) ^ sA;
  const float* xp = x + (size_t)(t0 + ta) * H + ko * 8;

  // B frag base for this wave/lane; per-k16 stride = 8192 halves
  const _Float16* const bb = wswz + (size_t)wave * 1024 + (size_t)lane * 8;

  f32x16 accA, accB;
#pragma unroll
  for (int r = 0; r < 16; ++r) { accA[r] = 0.0f; accB[r] = 0.0f; }

  f16x8 B[4][2];                     // 4 rotating phase slots x {hi,lo} = 32 VGPR

  auto writeA = [&](int buf, f32x4 q0, f32x4 q1) {
    const float v[8] = {q0[0], q0[1], q0[2], q0[3], q1[0], q1[1], q1[2], q1[3]};
    f16x8 hv, lv;
#pragma unroll
    for (int j = 0; j < 8; ++j) {
      const _Float16 h = (_Float16)v[j];
      hv[j] = h;
      lv[j] = (_Float16)((v[j] - (float)h) * LO_SCALE);
    }
    _Float16* p = &sm.a[buf][sA][0][posA * 8];
    *(f16x8*)p = hv;
    *(f16x8*)(p + 512) = lv;         // hl stride = 512 halves
  };

  // ---- prologue: A mega-tile 0 staged into buf 0, B phases 0-3 into slots ----
  {
    const f32x4 q0 = __builtin_nontemporal_load((const f32x4*)xp);
    const f32x4 q1 = __builtin_nontemporal_load((const f32x4*)xp + 1);
    writeA(0, q0, q1);
#pragma unroll
    for (int s = 0; s < 4; ++s) {
      const _Float16* bp = bb + (size_t)s * 8192;
      B[s][0] = *(const f16x8*)bp;
      B[s][1] = *(const f16x8*)(bp + 512);
    }
  }

  // ---- main loop: 32 mega-tiles, 1 barrier each ----
#pragma unroll 1
  for (int mt = 0; mt < NMT; ++mt) {
    const int buf = mt & 1;
    const bool more = (mt + 1 < NMT);
    f32x4 q0 = {}, q1 = {};
    if (more) {                      // x for mt+1: issue BEFORE the barrier
      xp += 128;
      q0 = __builtin_nontemporal_load((const f32x4*)xp);
      q1 = __builtin_nontemporal_load((const f32x4*)xp + 1);
    }
    __syncthreads();                 // A[buf] visible; prev reads retired
#pragma unroll
    for (int s = 0; s < 8; ++s) {    // s compile-time after unroll
      const int slot = s & 3;
      const int pos = (lane ^ s) * 8;
      const f16x8 ah = *(const f16x8*)&sm.a[buf][s][0][pos];
      const f16x8 al = *(const f16x8*)&sm.a[buf][s][1][pos];
      __builtin_amdgcn_s_setprio(1);
      accA = __builtin_amdgcn_mfma_f32_32x32x16_f16(ah, B[slot][0], accA, 0, 0, 0);
      accB = __builtin_amdgcn_mfma_f32_32x32x16_f16(ah, B[slot][1], accB, 0, 0, 0);
      accB = __builtin_amdgcn_mfma_f32_32x32x16_f16(al, B[slot][0], accB, 0, 0, 0);
      __builtin_amdgcn_s_setprio(0);
      // prefetch global phase 8*mt + s + 4 into the just-freed slot
      // (branchless tail clamp: redundant loads at the very end, never consumed)
      const int gp = 8 * mt + s + 4;
      const int gpc = gp < NK16 ? gp : NK16 - 1;
      const _Float16* bp = bb + (size_t)gpc * 8192;
      B[slot][0] = *(const f16x8*)bp;
      B[slot][1] = *(const f16x8*)(bp + 512);
      __builtin_amdgcn_sched_barrier(0);  // pin loads above next phase
    }
    if (more) writeA(buf ^ 1, q0, q1);
  }

  // ---- scores_for_choice into LDS (val overlays a_st: barrier first) ----
  __syncthreads();
  // C layout (32x32 MFMA): col = lane&31, row = (r&3) + 8*(r>>2) + 4*(lane>>5)
  {
    const int col = lane & 31;
    const int rbase = (lane >> 5) * 4;
    const int e = wave * 32 + col;
    const float be = sbias[e];
#pragma unroll
    for (int r = 0; r < 16; ++r) {
      const int row = (r & 3) + 8 * (r >> 2) + rbase;
      const float logit = accA[r] + accB[r] * LO_INV;
      const float s = 1.0f / (1.0f + expf(-logit));    // sigmoid
      sm.val[row][e] = s + be;                         // s_choice
    }
  }
  __syncthreads();

  // ---- grouped top-k, 16 threads per token (exact lax.top_k semantics) ----
  {
    const int tok = tid >> 4;        // 0..31
    const int tpt = tid & 15;        // sub-lane: experts [16*tpt, +16)
    const int base = lane & ~15;     // wave-lane base of this token's 16-group

    // cache my 16 experts in registers
    float lv[16];
#pragma unroll
    for (int j = 0; j < 16; ++j) lv[j] = sm.val[tok][tpt * 16 + j];

    // local top-2 of my 16 (group g = tpt>>1 spans sub-lanes 2g, 2g+1)
    float m1 = -1e30f, m2 = -1e30f;
#pragma unroll
    for (int j = 0; j < 16; ++j) {
      const float v = lv[j];
      if (v > m1) { m2 = m1; m1 = v; }
      else if (v > m2) { m2 = v; }
    }
    // merge with partner sub-lane -> group top-2 sum (both lanes identical)
    const float o1 = __shfl_xor(m1, 1);
    const float o2 = __shfl_xor(m2, 1);
    const float g1 = fmaxf(m1, o1);
    const float g2 = fmaxf(fminf(m1, o1), (m1 >= o1) ? m2 : o2);
    const float gsum = g1 + g2;

    // gather all 8 group sums (from sub-lanes 0,2,4,...,14)
    float gsv[NGROUP];
#pragma unroll
    for (int g = 0; g < NGROUP; ++g) gsv[g] = __shfl(gsum, base + 2 * g);

    // top-4 groups, redundantly on every lane (identical result)
    unsigned selmask = 0;
#pragma unroll
    for (int r = 0; r < TOPK_GROUP; ++r) {
      float best = -1e30f; int bg = 0;
#pragma unroll
      for (int g = 0; g < NGROUP; ++g) {
        if (((selmask >> g) & 1u) == 0 && gsv[g] > best) { best = gsv[g]; bg = g; }
      }
      selmask |= 1u << bg;
    }

    // masked candidate values for my 16 experts (group not selected -> 0.0)
    const bool gsel = (selmask >> (tpt >> 1)) & 1u;
    float mv[16];
#pragma unroll
    for (int j = 0; j < 16; ++j) mv[j] = gsel ? lv[j] : 0.0f;

    // 8 argmax rounds; lowest index wins ties (matches ascending > scan)
    unsigned mymask = 0;
    int my_idx = 0;
    float my_w = 0.f, wsum = 0.f;
    for (int r = 0; r < TOPK; ++r) {
      float best = -1e30f; int bj = 0;
#pragma unroll
      for (int j = 0; j < 16; ++j) {
        if ((mymask >> j) & 1u) continue;
        if (mv[j] > best) { best = mv[j]; bj = j; }
      }
      int bidx = tpt * 16 + bj;
#pragma unroll
      for (int d = 1; d < 16; d <<= 1) {
        const float ov = __shfl_xor(best, d);
        const int oi = __shfl_xor(bidx, d);
        if (ov > best || (ov == best && oi < bidx)) { best = ov; bidx = oi; }
      }
      if ((bidx >> 4) == tpt) mymask |= 1u << (bidx & 15);
      const float s = sm.val[tok][bidx] - sbias[bidx];  // broadcast read
      wsum += s;
      if (tpt == r) { my_idx = bidx; my_w = s; }
    }
    const float inv = SCALE / (wsum + 1e-20f);
    if (tpt < TOPK) {
      out_idx[(t0 + tok) * TOPK + tpt] = (float)my_idx;
      out_w[(t0 + tok) * TOPK + tpt] = my_w * inv;
    }
  }
}

extern "C" void kernel_launch(void* const* d_in, const int* in_sizes, int n_in,
                              void* d_out, int out_size, void* d_ws, size_t ws_size,
                              hipStream_t stream) {
  const float* x = (const float*)d_in[0];     // (4,4096,4096) fp32
  const float* w = (const float*)d_in[1];     // (256,4096) fp32
  const float* bias = (const float*)d_in[2];  // (256,) fp32

  const int T = in_sizes[0] / H;              // 16384
  _Float16* wswz = (_Float16*)d_ws;           // 4 MB frag-linear hi/lo W
  float* out_idx = (float*)d_out;
  float* out_w = (float*)d_out + (size_t)T * TOPK;

  prep_w_kernel<<<dim3(NK16, E / 32), dim3(64), 0, stream>>>(w, wswz);
  moe_gate_kernel<<<dim3(T / BM), dim3(NTH), 0, stream>>>(x, wswz, bias, out_idx, out_w);
}

// Round 6
// 410.007 us; speedup vs baseline: 1.4861x; 1.0464x over previous
//
#include <hip/hip_runtime.h>
#include <math.h>

// GlmDSAMoEGate, round 9: halve the L2 B-traffic (the measured next floor).
// R8 (~150us kernel): BM=32, 2 blk/CU -> B reads 8MB/CU from L2 = 85 B/cy/CU,
// above the ~56 B/cy per-CU L2 ceiling -> L2-bound at ~60us floor + stalls.
// R9: BM=64, grid=256, 1 blk/CU -> 4MB/CU (42 B/cy < ceiling). MFMA floor 41us,
// LDS floor 41us (separate pipe), HBM ~25-40us -> target 65-95us.
// The R5 "1 blk/CU trap" is defused by the (R8-proven) register B pipeline +
// NEW A-fragment read-ahead: phase s+1's 4 ds_read_b128 issue before phase s's
// MFMA cluster (double reg set, statically indexed under full unroll), so
// 2 waves/SIMD suffice to cover LDS latency.
//  - B: 4 rotating slots (32 VGPR), prefetch distance 4 phases (~1500cy >= L2
//    latency); sched_barrier(0) per phase pins the schedule; setprio(1) on MFMA.
//  - A staging: exact R8 pattern per 32-token half, applied twice (mt=0,1).
//  - Epilogue: 8 threads/token; each sub-lane owns one full group of 32.
// Math: fp32 -> fp16 hi + lo*2^12 split, 3 MFMA passes, logit = accA+accB*2^-12
// (passed R4/R5/R7/R8, absmax 2e-3).

constexpr int H = 4096;
constexpr int E = 256;
constexpr int BM = 64;          // tokens per block
constexpr int NTH = 512;        // 8 waves
constexpr int TOPK = 8;
constexpr int NGROUP = 8;
constexpr int GSIZE = 32;
constexpr int TOPK_GROUP = 4;
constexpr float SCALE = 2.5f;
constexpr int NK16 = H / 16;    // 256 k16 slabs (global phases)
constexpr int NMT = H / 128;    // 32 K-mega-tiles
constexpr float LO_SCALE = 4096.0f;       // 2^12
constexpr float LO_INV = 1.0f / 4096.0f;  // 2^-12

typedef _Float16 f16x8 __attribute__((ext_vector_type(8)));
typedef float f32x4 __attribute__((ext_vector_type(4)));
typedef float f32x16 __attribute__((ext_vector_type(16)));

// ---------------- kernel 0: W[E][H] fp32 -> fragment-linear fp16 hi/lo ------
// Frag for MFMA 32x32x16 tile (k16, n32): lane l holds B[k][n] with
// n = n32*32 + (l&31), k = k16*16 + (l>>5)*8 + j, j=0..7  (16B per lane).
// Layout: wswz[(k16*8 + n32)*1024 + hl*512 + l*8]  (halves). Total 4MB.
__global__ __launch_bounds__(64)
void prep_w_kernel(const float* __restrict__ w, _Float16* __restrict__ wswz) {
  const int l = threadIdx.x;        // 0..63
  const int k16 = blockIdx.x;       // 0..255
  const int n32 = blockIdx.y;       // 0..7
  const int e = n32 * 32 + (l & 31);
  const int h0 = k16 * 16 + (l >> 5) * 8;
  const float4* wp = (const float4*)(w + (size_t)e * H + h0);
  const float4 a = wp[0], b = wp[1];
  const float v[8] = {a.x, a.y, a.z, a.w, b.x, b.y, b.z, b.w};
  f16x8 hi, lo;
#pragma unroll
  for (int j = 0; j < 8; ++j) {
    const _Float16 h = (_Float16)v[j];
    hi[j] = h;
    lo[j] = (_Float16)((v[j] - (float)h) * LO_SCALE);  // exact residual, scaled
  }
  _Float16* dst = wswz + (size_t)(k16 * 8 + n32) * 1024 + (size_t)l * 8;
  *(f16x8*)dst = hi;
  *(f16x8*)(dst + 512) = lo;
}

// ---------------- kernel 1: fused gate -------------------------------------
__global__ __launch_bounds__(NTH, 2)
void moe_gate_kernel(const float* __restrict__ x,      // [T][H] fp32
                     const _Float16* __restrict__ wswz,// frag-linear hi/lo
                     const float* __restrict__ bias,   // [E]
                     float* __restrict__ out_idx,      // [T][8] (as float)
                     float* __restrict__ out_w) {      // [T][8]
  // a: [buf][s 0..7][mt 0..1][hl][512 halves] = 64 KB
  // val: scores_for_choice, 64*257*4 = 65792 B.  Disjoint in time -> union.
  __shared__ __align__(16) union SM {
    _Float16 a[2][8][2][2][512];
    float val[BM][E + 1];
  } sm;
  __shared__ float sbias[E];

  const int tid = threadIdx.x;
  const int lane = tid & 63;
  const int wave = tid >> 6;         // 0..7 -> expert slice [32*wave, +32)
  const long t0 = (long)blockIdx.x * BM;

  if (tid < E) sbias[tid] = bias[tid];

  // A staging coords (R8 pattern, applied per 32-token half):
  // thread -> (token ta in 0..31, k-octet ko in 0..15), 8 floats = 32B of x.
  // Chunk c = kh*32 + ta (kh = ko&1), phase s = ko>>1. Write pos = c ^ s,
  // read pos = lane ^ s (XOR swizzle; reads permuted-contiguous, conflict-free).
  const int ta = tid >> 4;           // 0..31 token (half 0); half 1 = ta+32
  const int ko = tid & 15;           // 0..15 k-octet within 128-k mega-tile
  const int sA = ko >> 1;            // k16 phase 0..7
  const int posA = (((ko & 1) << 5) | ta) ^ sA;
  const float* xp0 = x + (size_t)(t0 + ta) * H + ko * 8;        // token ta
  const float* xp1 = xp0 + (size_t)32 * H;                      // token ta+32

  // B frag base for this wave/lane; per-k16 stride = 8192 halves
  const _Float16* const bb = wswz + (size_t)wave * 1024 + (size_t)lane * 8;

  f32x16 accA[2], accB[2];           // [mt] - 64 VGPR
#pragma unroll
  for (int mt = 0; mt < 2; ++mt)
#pragma unroll
    for (int r = 0; r < 16; ++r) { accA[mt][r] = 0.0f; accB[mt][r] = 0.0f; }

  f16x8 B[4][2];                     // 4 rotating phase slots x {hi,lo} = 32 VGPR

  auto writeA = [&](int buf, int mt, f32x4 qa, f32x4 qb) {
    const float v[8] = {qa[0], qa[1], qa[2], qa[3], qb[0], qb[1], qb[2], qb[3]};
    f16x8 hv, lv;
#pragma unroll
    for (int j = 0; j < 8; ++j) {
      const _Float16 h = (_Float16)v[j];
      hv[j] = h;
      lv[j] = (_Float16)((v[j] - (float)h) * LO_SCALE);
    }
    _Float16* p = &sm.a[buf][sA][mt][0][posA * 8];
    *(f16x8*)p = hv;
    *(f16x8*)(p + 512) = lv;         // hl stride = 512 halves
  };

  // ---- prologue: A mega-tile 0 staged into buf 0, B phases 0-3 into slots ----
  {
    const f32x4 q0 = __builtin_nontemporal_load((const f32x4*)xp0);
    const f32x4 q1 = __builtin_nontemporal_load((const f32x4*)xp0 + 1);
    const f32x4 q2 = __builtin_nontemporal_load((const f32x4*)xp1);
    const f32x4 q3 = __builtin_nontemporal_load((const f32x4*)xp1 + 1);
    writeA(0, 0, q0, q1);
    writeA(0, 1, q2, q3);
#pragma unroll
    for (int s = 0; s < 4; ++s) {
      const _Float16* bp = bb + (size_t)s * 8192;
      B[s][0] = *(const f16x8*)bp;
      B[s][1] = *(const f16x8*)(bp + 512);
    }
  }

  // ---- main loop: 32 mega-tiles, 1 barrier each ----
#pragma unroll 1
  for (int mt = 0; mt < NMT; ++mt) {
    const int buf = mt & 1;
    const bool more = (mt + 1 < NMT);
    f32x4 q0 = {}, q1 = {}, q2 = {}, q3 = {};
    if (more) {                      // x for mt+1: issue BEFORE the barrier
      xp0 += 128;
      xp1 += 128;
      q0 = __builtin_nontemporal_load((const f32x4*)xp0);
      q1 = __builtin_nontemporal_load((const f32x4*)xp0 + 1);
      q2 = __builtin_nontemporal_load((const f32x4*)xp1);
      q3 = __builtin_nontemporal_load((const f32x4*)xp1 + 1);
    }
    __syncthreads();                 // A[buf] visible; prev reads retired

    f16x8 af[2][2][2];               // [par][mt][hl] read-ahead sets, static idx
    {
      const int pos0 = (lane ^ 0) * 8;
      af[0][0][0] = *(const f16x8*)&sm.a[buf][0][0][0][pos0];
      af[0][0][1] = *(const f16x8*)&sm.a[buf][0][0][1][pos0];
      af[0][1][0] = *(const f16x8*)&sm.a[buf][0][1][0][pos0];
      af[0][1][1] = *(const f16x8*)&sm.a[buf][0][1][1][pos0];
    }
#pragma unroll
    for (int s = 0; s < 8; ++s) {    // all indices compile-time after unroll
      const int par = s & 1, nxt = par ^ 1, slot = s & 3;
      if (s < 7) {                   // read-ahead phase s+1 A-frags
        const int pos = (lane ^ (s + 1)) * 8;
        af[nxt][0][0] = *(const f16x8*)&sm.a[buf][s + 1][0][0][pos];
        af[nxt][0][1] = *(const f16x8*)&sm.a[buf][s + 1][0][1][pos];
        af[nxt][1][0] = *(const f16x8*)&sm.a[buf][s + 1][1][0][pos];
        af[nxt][1][1] = *(const f16x8*)&sm.a[buf][s + 1][1][1][pos];
      }
      __builtin_amdgcn_s_setprio(1);
      accA[0] = __builtin_amdgcn_mfma_f32_32x32x16_f16(af[par][0][0], B[slot][0], accA[0], 0, 0, 0);
      accA[1] = __builtin_amdgcn_mfma_f32_32x32x16_f16(af[par][1][0], B[slot][0], accA[1], 0, 0, 0);
      accB[0] = __builtin_amdgcn_mfma_f32_32x32x16_f16(af[par][0][0], B[slot][1], accB[0], 0, 0, 0);
      accB[1] = __builtin_amdgcn_mfma_f32_32x32x16_f16(af[par][1][0], B[slot][1], accB[1], 0, 0, 0);
      accB[0] = __builtin_amdgcn_mfma_f32_32x32x16_f16(af[par][0][1], B[slot][0], accB[0], 0, 0, 0);
      accB[1] = __builtin_amdgcn_mfma_f32_32x32x16_f16(af[par][1][1], B[slot][0], accB[1], 0, 0, 0);
      __builtin_amdgcn_s_setprio(0);
      // prefetch global phase 8*mt+s+4 into the just-freed slot
      // (branchless tail clamp: redundant loads at the end, never consumed)
      const int gp = 8 * mt + s + 4;
      const int gpc = gp < NK16 ? gp : NK16 - 1;
      const _Float16* bp = bb + (size_t)gpc * 8192;
      B[slot][0] = *(const f16x8*)bp;
      B[slot][1] = *(const f16x8*)(bp + 512);
      __builtin_amdgcn_sched_barrier(0);  // pin phase schedule
    }
    if (more) {
      writeA(buf ^ 1, 0, q0, q1);
      writeA(buf ^ 1, 1, q2, q3);
    }
  }

  // ---- scores_for_choice into LDS (val overlays a_st: barrier first) ----
  __syncthreads();
  // C layout (32x32 MFMA): col = lane&31, row = (r&3) + 8*(r>>2) + 4*(lane>>5)
  {
    const int col = lane & 31;
    const int rbase = (lane >> 5) * 4;
    const int e = wave * 32 + col;
    const float be = sbias[e];
#pragma unroll
    for (int mt = 0; mt < 2; ++mt)
#pragma unroll
      for (int r = 0; r < 16; ++r) {
        const int row = (r & 3) + 8 * (r >> 2) + rbase;
        const float logit = accA[mt][r] + accB[mt][r] * LO_INV;
        const float s = 1.0f / (1.0f + expf(-logit));    // sigmoid
        sm.val[mt * 32 + row][e] = s + be;               // s_choice
      }
  }
  __syncthreads();

  // ---- grouped top-k, 8 threads per token (exact lax.top_k semantics) ----
  {
    const int tok = tid >> 3;        // 0..63
    const int tpt = tid & 7;         // sub-lane == group g; experts [32*tpt,+32)
    const int base = lane & ~7;      // wave-lane base of this token's 8-cluster

    // cache my group's 32 experts in registers
    float lv[GSIZE];
#pragma unroll
    for (int j = 0; j < GSIZE; ++j) lv[j] = sm.val[tok][tpt * GSIZE + j];

    // group top-2 sum, fully local (one group per sub-lane)
    float m1 = -1e30f, m2 = -1e30f;
#pragma unroll
    for (int j = 0; j < GSIZE; ++j) {
      const float v = lv[j];
      if (v > m1) { m2 = m1; m1 = v; }
      else if (v > m2) { m2 = v; }
    }
    const float gsum = m1 + m2;

    // gather all 8 group sums
    float gsv[NGROUP];
#pragma unroll
    for (int g = 0; g < NGROUP; ++g) gsv[g] = __shfl(gsum, base + g);

    // top-4 groups, redundantly on every lane (identical result, ties->low idx)
    unsigned selmask = 0;
#pragma unroll
    for (int r = 0; r < TOPK_GROUP; ++r) {
      float best = -1e30f; int bg = 0;
#pragma unroll
      for (int g = 0; g < NGROUP; ++g) {
        if (((selmask >> g) & 1u) == 0 && gsv[g] > best) { best = gsv[g]; bg = g; }
      }
      selmask |= 1u << bg;
    }

    // masked candidates for my group (not selected -> 0.0, matches jnp.where)
    const bool gsel = (selmask >> tpt) & 1u;
    float mv[GSIZE];
#pragma unroll
    for (int j = 0; j < GSIZE; ++j) mv[j] = gsel ? lv[j] : 0.0f;

    // 8 argmax rounds; lowest index wins ties (matches ascending > scan)
    unsigned mymask = 0;
    int my_idx = 0;
    float my_w = 0.f, wsum = 0.f;
    for (int r = 0; r < TOPK; ++r) {
      float best = -1e30f; int bj = 0;
#pragma unroll
      for (int j = 0; j < GSIZE; ++j) {
        if ((mymask >> j) & 1u) continue;
        if (mv[j] > best) { best = mv[j]; bj = j; }
      }
      int bidx = tpt * GSIZE + bj;
#pragma unroll
      for (int d = 1; d < 8; d <<= 1) {
        const float ov = __shfl_xor(best, d);
        const int oi = __shfl_xor(bidx, d);
        if (ov > best || (ov == best && oi < bidx)) { best = ov; bidx = oi; }
      }
      if ((bidx >> 5) == tpt) mymask |= 1u << (bidx & 31);
      const float s = sm.val[tok][bidx] - sbias[bidx];  // broadcast read
      wsum += s;
      if (tpt == r) { my_idx = bidx; my_w = s; }
    }
    const float inv = SCALE / (wsum + 1e-20f);
    out_idx[(t0 + tok) * TOPK + tpt] = (float)my_idx;   // tpt == output slot r
    out_w[(t0 + tok) * TOPK + tpt] = my_w * inv;
  }
}

extern "C" void kernel_launch(void* const* d_in, const int* in_sizes, int n_in,
                              void* d_out, int out_size, void* d_ws, size_t ws_size,
                              hipStream_t stream) {
  const float* x = (const float*)d_in[0];     // (4,4096,4096) fp32
  const float* w = (const float*)d_in[1];     // (256,4096) fp32
  const float* bias = (const float*)d_in[2];  // (256,) fp32

  const int T = in_sizes[0] / H;              // 16384
  _Float16* wswz = (_Float16*)d_ws;           // 4 MB frag-linear hi/lo W
  float* out_idx = (float*)d_out;
  float* out_w = (float*)d_out + (size_t)T * TOPK;

  prep_w_kernel<<<dim3(NK16, E / 32), dim3(64), 0, stream>>>(w, wswz);
  moe_gate_kernel<<<dim3(T / BM), dim3(NTH), 0, stream>>>(x, wswz, bias, out_idx, out_w);
}